// Round 5
// baseline (478.666 us; speedup 1.0000x reference)
//
#include <hip/hip_runtime.h>
#include <hip/hip_bf16.h>
#include <math.h>

// Problem constants
#define NHEAD 16
#define DHEAD 64
#define HIDDEN 1024
#define TSEQ 2048
#define BATCH 4
#define QKV_OUT 2112   // (2*16+1)*64
#define BT (BATCH * TSEQ)  // 8192

typedef __attribute__((ext_vector_type(8))) short bf16x8;
typedef __attribute__((ext_vector_type(4))) float floatx4;

static __device__ __forceinline__ short f2bf(float x) {
  __hip_bfloat16 h = __float2bfloat16(x);
  return *reinterpret_cast<short*>(&h);
}

#define MFMA16(a, b, c) __builtin_amdgcn_mfma_f32_16x16x32_bf16(a, b, c, 0, 0, 0)

// ---------------------------------------------------------------------------
// fp32 -> bf16 conversion, 8 elems/thread. n must be divisible by 8.
// ---------------------------------------------------------------------------
__global__ __launch_bounds__(256) void f32_to_bf16(
    const float* __restrict__ src, short* __restrict__ dst, int n) {
  const int i = (blockIdx.x * 256 + threadIdx.x) * 8;
  if (i >= n) return;
  float4 a = *(const float4*)&src[i];
  float4 b = *(const float4*)&src[i + 4];
  short o[8];
  o[0] = f2bf(a.x); o[1] = f2bf(a.y); o[2] = f2bf(a.z); o[3] = f2bf(a.w);
  o[4] = f2bf(b.x); o[5] = f2bf(b.y); o[6] = f2bf(b.z); o[7] = f2bf(b.w);
  *(uint4*)&dst[i] = *(uint4*)o;
}

// ---------------------------------------------------------------------------
// MFMA bf16 GEMM: C[M][N] = A[M][K] @ B[N][K]^T + bias[N].
// BM=128, BN=64, BK=64; 4 waves 2x2; wave tile 64x32. Pad 72 shorts/row.
// (Round-0 verified version. Do NOT grow the tile: acc[4][4] + prefetch regs
//  spilled to scratch in round 2 — 515 MB of scratch WRITE_SIZE.)
// ---------------------------------------------------------------------------
#define QK_BM 128
#define QK_BN 64
#define QK_BK 64

template <typename OUT_T>
__global__ __launch_bounds__(256) void gemm_mfma_bf16(
    const short* __restrict__ A, const short* __restrict__ B,
    const float* __restrict__ bias, OUT_T* __restrict__ C,
    int M, int N, int K) {
  __shared__ short As[QK_BM][72];
  __shared__ short Bs[QK_BN][72];

  const int tid = threadIdx.x;
  const int lane = tid & 63;
  const int wv = tid >> 6;
  const int ln = lane & 15;
  const int grp = lane >> 4;
  const int wm = wv >> 1;
  const int wn = wv & 1;
  const int rowbase = blockIdx.y * QK_BM;
  const int colbase = blockIdx.x * QK_BN;

  const int ar = tid >> 1, ac = (tid & 1) * 32;
  const int br = tid >> 2, bc = (tid & 3) * 16;

  floatx4 acc[4][2];
#pragma unroll
  for (int m = 0; m < 4; ++m)
#pragma unroll
    for (int n = 0; n < 2; ++n) acc[m][n] = (floatx4){0.f, 0.f, 0.f, 0.f};

  for (int k0 = 0; k0 < K; k0 += QK_BK) {
    const short* ap = A + (size_t)(rowbase + ar) * K + k0 + ac;
    uint4 a0 = *(const uint4*)(ap + 0);
    uint4 a1 = *(const uint4*)(ap + 8);
    uint4 a2 = *(const uint4*)(ap + 16);
    uint4 a3 = *(const uint4*)(ap + 24);
    const short* bp = B + (size_t)(colbase + br) * K + k0 + bc;
    uint4 b0 = *(const uint4*)(bp + 0);
    uint4 b1 = *(const uint4*)(bp + 8);
    __syncthreads();
    *(uint4*)&As[ar][ac + 0] = a0;
    *(uint4*)&As[ar][ac + 8] = a1;
    *(uint4*)&As[ar][ac + 16] = a2;
    *(uint4*)&As[ar][ac + 24] = a3;
    *(uint4*)&Bs[br][bc + 0] = b0;
    *(uint4*)&Bs[br][bc + 8] = b1;
    __syncthreads();

#pragma unroll
    for (int ks = 0; ks < 2; ++ks) {
      bf16x8 bfrag[2];
#pragma unroll
      for (int n = 0; n < 2; ++n)
        bfrag[n] = *(const bf16x8*)&Bs[wn * 32 + n * 16 + ln][ks * 32 + grp * 8];
#pragma unroll
      for (int m = 0; m < 4; ++m) {
        bf16x8 af = *(const bf16x8*)&As[wm * 64 + m * 16 + ln][ks * 32 + grp * 8];
#pragma unroll
        for (int n = 0; n < 2; ++n)
          acc[m][n] = MFMA16(af, bfrag[n], acc[m][n]);
      }
    }
  }

#pragma unroll
  for (int n = 0; n < 2; ++n) {
    const int col = colbase + wn * 32 + n * 16 + ln;
    const float bv = bias[col];
#pragma unroll
    for (int m = 0; m < 4; ++m) {
#pragma unroll
      for (int r = 0; r < 4; ++r) {
        const int row = rowbase + wm * 64 + m * 16 + grp * 4 + r;
        const float v = acc[m][n][r] + bv;
        if constexpr (sizeof(OUT_T) == 2)
          C[(size_t)row * N + col] = f2bf(v);
        else
          C[(size_t)row * N + col] = v;
      }
    }
  }
}

// ---------------------------------------------------------------------------
// Transpose V: vt[b][d][t] = qkv_bf16[b*T + t][2048 + d]
// ---------------------------------------------------------------------------
__global__ __launch_bounds__(256) void transpose_v(
    const short* __restrict__ qkv, short* __restrict__ vt) {
  __shared__ short tile[64][72];
  const int tt = blockIdx.x;
  const int b = blockIdx.y;
  const int tid = threadIdx.x;
  const int li = tid >> 2;
  const int lc = (tid & 3) * 16;

  const short* src = qkv + (size_t)(b * TSEQ + tt * 64 + li) * QKV_OUT + 2048 + lc;
  *(uint4*)&tile[li][lc] = *(const uint4*)src;
  *(uint4*)&tile[li][lc + 8] = *(const uint4*)(src + 8);
  __syncthreads();
  short tmp[16];
#pragma unroll
  for (int u = 0; u < 16; ++u) tmp[u] = tile[lc + u][li];
  short* dst = vt + (size_t)(b * 64 + li) * TSEQ + tt * 64 + lc;
  *(uint4*)dst = *(uint4*)&tmp[0];
  *(uint4*)(dst + 8) = *(uint4*)&tmp[8];
}

// ---------------------------------------------------------------------------
// Split-j MFMA bf16 causal flash attention, ZERO-BARRIER variant.
// K and V fragments are read DIRECTLY from global (L2-resident working sets:
// K = 256 KB/(b,h); V = 256 KB/batch shared by 16 heads). The per-lane 16B
// fragment reads touch 16 fully-consumed 64B lines per instruction — same
// line count as a coalesced load. Only Ps (wave-private rows, same-wave
// write->read, in-order DS) stays in LDS -> no __syncthreads anywhere,
// LDS 9216 B -> 8 blocks/CU residency, TLP does the latency hiding.
// Block = ((it,jc), h, b): 64 q-rows, <=8 j-tiles.
// it<8 (single chunk): write normalized attn_vec directly.
// it>=8: write unnormalized O^T (fp32) + l to partial workspace.
// ---------------------------------------------------------------------------
#define CH 8  // j-tiles per chunk

__global__ __launch_bounds__(256) void attn_partial(
    const short* __restrict__ qkv, const short* __restrict__ vt,
    float* __restrict__ attn_vec, float* __restrict__ pO,
    float* __restrict__ pL) {
  __shared__ short Ps[64][72];  // [q][j], per-wave 16-row slices

  const int x = gridDim.x - 1 - blockIdx.x;  // big-it blocks dispatch first
  int it, jc;
  if (x < 8) {
    it = x; jc = 0;
  } else if (x < 24) {
    it = 8 + ((x - 8) >> 1); jc = (x - 8) & 1;
  } else if (x < 48) {
    it = 16 + (x - 24) / 3; jc = (x - 24) % 3;
  } else {
    it = 24 + ((x - 48) >> 2); jc = (x - 48) & 3;
  }
  const int jstart = jc * CH;
  const int jend = min(jstart + CH, it + 1);

  const int tid = threadIdx.x;
  const int h = blockIdx.y;
  const int b = blockIdx.z;
  const int lane = tid & 63;
  const int wv = tid >> 6;
  const int ln = lane & 15;
  const int grp = lane >> 4;
  const int qbase = wv * 16;
  const float CEXP = 0.18033688f;  // 0.125 * log2(e)

  // Q B-fragment (persistent): B[k=d][n=q]
  const short* qptr = qkv + (size_t)(b * TSEQ + it * 64 + qbase + ln) * QKV_OUT + h * 64;
  const bf16x8 bq0 = *(const bf16x8*)(qptr + grp * 8);
  const bf16x8 bq1 = *(const bf16x8*)(qptr + 32 + grp * 8);

  // per-lane fragment base pointers within the first 64x64 tile of the chunk
  // K: qkv[(b*T + jt*64 + frag_row)*QKV_OUT + 1024 + h*64 + grp*8]
  const short* kb0 = qkv + (size_t)(b * TSEQ + jstart * 64 + 0) * QKV_OUT + 1024 +
                     h * 64 + (size_t)ln * QKV_OUT + grp * 8;
  // V: vt[(b*64 + frag_row)*T + jt*64 + grp*8]
  const short* vb0 = vt + ((size_t)b * 64 + ln) * TSEQ + (size_t)jstart * 64 + grp * 8;
  const size_t kmstep = (size_t)16 * QKV_OUT;  // K-frag row stride per m-tile
  const size_t vmstep = (size_t)16 * TSEQ;     // V-frag row stride per m-tile

  floatx4 oT[4];
#pragma unroll
  for (int m = 0; m < 4; ++m) oT[m] = (floatx4){0.f, 0.f, 0.f, 0.f};
  float lsum = 0.f;

  for (int jt = jstart; jt < jend; ++jt) {
    const short* kb = kb0 + (size_t)(jt - jstart) * 64 * QKV_OUT;
    const short* vb = vb0 + (size_t)(jt - jstart) * 64;

    // S^T = K @ Q^T: 4 m-tiles (j), 2 k-steps (d); K-frags direct from global
    floatx4 st[4];
#pragma unroll
    for (int m = 0; m < 4; ++m) {
      bf16x8 ak0 = *(const bf16x8*)(kb + m * kmstep);
      bf16x8 ak1 = *(const bf16x8*)(kb + m * kmstep + 32);
      floatx4 a = (floatx4){0.f, 0.f, 0.f, 0.f};
      a = MFMA16(ak0, bq0, a);
      a = MFMA16(ak1, bq1, a);
      st[m] = a;
    }

    // causal mask on diagonal tile: j-local > q-local -> -inf
    if (jt == it) {
#pragma unroll
      for (int m = 0; m < 4; ++m)
#pragma unroll
        for (int r = 0; r < 4; ++r)
          if (m * 16 + grp * 4 + r > qbase + ln) st[m][r] = -INFINITY;
    }

    // P = exp2(CEXP * s), accumulate l, packed bf16x4 store to Ps
#pragma unroll
    for (int m = 0; m < 4; ++m) {
      float p0 = exp2f(CEXP * st[m][0]);
      float p1 = exp2f(CEXP * st[m][1]);
      float p2 = exp2f(CEXP * st[m][2]);
      float p3 = exp2f(CEXP * st[m][3]);
      lsum += (p0 + p1) + (p2 + p3);
      short pk[4] = {f2bf(p0), f2bf(p1), f2bf(p2), f2bf(p3)};
      *(uint2*)&Ps[qbase + ln][m * 16 + grp * 4] = *(uint2*)pk;
    }

    // O^T += V^T(A) @ P^T(B); V-frags direct from global (L2-hot, h-shared)
    bf16x8 bp0 = *(const bf16x8*)&Ps[qbase + ln][grp * 8];
    bf16x8 bp1 = *(const bf16x8*)&Ps[qbase + ln][32 + grp * 8];
#pragma unroll
    for (int m = 0; m < 4; ++m) {
      bf16x8 av0 = *(const bf16x8*)(vb + m * vmstep);
      bf16x8 av1 = *(const bf16x8*)(vb + m * vmstep + 32);
      oT[m] = MFMA16(av0, bp0, oT[m]);
      oT[m] = MFMA16(av1, bp1, oT[m]);
    }
  }

  // reduce l across grp (lanes with same ln share q)
  lsum += __shfl_xor(lsum, 16);
  lsum += __shfl_xor(lsum, 32);

  if (it < 8) {
    // single chunk: normalize and write attn_vec directly
    const float inv = 1.f / lsum;
    float* orow =
        attn_vec + ((size_t)(b * NHEAD + h) * TSEQ + it * 64 + qbase + ln) * DHEAD;
#pragma unroll
    for (int m = 0; m < 4; ++m) {
      float4 o4;
      o4.x = oT[m][0] * inv;
      o4.y = oT[m][1] * inv;
      o4.z = oT[m][2] * inv;
      o4.w = oT[m][3] * inv;
      *(float4*)&orow[m * 16 + grp * 4] = o4;
    }
  } else {
    // write unnormalized partial
    const int slot = (it < 16) ? (it - 8) * 2 + jc
                   : (it < 24) ? 16 + (it - 16) * 3 + jc
                               : 40 + (it - 24) * 4 + jc;
    const size_t sbase = (size_t)(b * NHEAD + h) * 72 + slot;
    float* prow = pO + sbase * 4096 + (size_t)(qbase + ln) * 64;
#pragma unroll
    for (int m = 0; m < 4; ++m) {
      float4 o4;
      o4.x = oT[m][0]; o4.y = oT[m][1]; o4.z = oT[m][2]; o4.w = oT[m][3];
      *(float4*)&prow[m * 16 + grp * 4] = o4;
    }
    if (grp == 0) pL[sbase * 64 + qbase + ln] = lsum;
  }
}

// ---------------------------------------------------------------------------
// Combine partials for it>=8: sum O^T chunks + l, normalize, write attn_vec.
// Block = (it-8, h, b); thread -> q = tid>>2, 16 d-cols.
// ---------------------------------------------------------------------------
__global__ __launch_bounds__(256) void attn_combine(
    const float* __restrict__ pO, const float* __restrict__ pL,
    float* __restrict__ attn_vec) {
  const int it = 8 + blockIdx.x;  // 8..31
  const int h = blockIdx.y;
  const int b = blockIdx.z;
  const int nch = (it < 16) ? 2 : (it < 24) ? 3 : 4;
  const int slot0 = (it < 16) ? (it - 8) * 2
                  : (it < 24) ? 16 + (it - 16) * 3
                              : 40 + (it - 24) * 4;
  const int q = threadIdx.x >> 2;
  const int dbase = (threadIdx.x & 3) * 16;
  const size_t base = (size_t)(b * NHEAD + h) * 72 + slot0;

  float4 acc[4];
#pragma unroll
  for (int u = 0; u < 4; ++u) acc[u] = (float4){0.f, 0.f, 0.f, 0.f};
  float l = 0.f;
  for (int c = 0; c < nch; ++c) {
    const float* pr = pO + (base + c) * 4096 + (size_t)q * 64 + dbase;
#pragma unroll
    for (int u = 0; u < 4; ++u) {
      float4 v = *(const float4*)&pr[u * 4];
      acc[u].x += v.x; acc[u].y += v.y; acc[u].z += v.z; acc[u].w += v.w;
    }
    l += pL[(base + c) * 64 + q];
  }
  const float inv = 1.f / l;
  float* orow =
      attn_vec + ((size_t)(b * NHEAD + h) * TSEQ + it * 64 + q) * DHEAD + dbase;
#pragma unroll
  for (int u = 0; u < 4; ++u) {
    float4 o4;
    o4.x = acc[u].x * inv; o4.y = acc[u].y * inv;
    o4.z = acc[u].z * inv; o4.w = acc[u].w * inv;
    *(float4*)&orow[u * 4] = o4;
  }
}

// ---------------------------------------------------------------------------
// Mean over heads -> bf16 (feeds the MFMA out-projection). 2 elems/thread.
// ---------------------------------------------------------------------------
__global__ __launch_bounds__(256) void mean_heads(
    const float* __restrict__ attn_vec, short* __restrict__ m) {
  const int gid = blockIdx.x * 256 + threadIdx.x;  // over BT*64/2
  const int d2 = (gid & 31) * 2;
  const int t = (gid >> 5) & (TSEQ - 1);
  const int b = gid >> 16;
  float s0 = 0.f, s1 = 0.f;
#pragma unroll
  for (int h = 0; h < NHEAD; ++h) {
    const float* p = &attn_vec[(((size_t)(b * NHEAD + h) * TSEQ) + t) * DHEAD + d2];
    s0 += p[0];
    s1 += p[1];
  }
  short pk[2] = {f2bf(s0 * (1.f / 16.f)), f2bf(s1 * (1.f / 16.f))};
  *(uint*)&m[gid * 2] = *(uint*)pk;
}

// ---------------------------------------------------------------------------
extern "C" void kernel_launch(void* const* d_in, const int* in_sizes, int n_in,
                              void* d_out, int out_size, void* d_ws, size_t ws_size,
                              hipStream_t stream) {
  const float* x     = (const float*)d_in[0];  // [4,2048,1024]
  const float* w_qkv = (const float*)d_in[1];  // [2112,1024]
  const float* b_qkv = (const float*)d_in[2];  // [2112]
  const float* w_out = (const float*)d_in[3];  // [1024,64]
  const float* b_out = (const float*)d_in[4];  // [1024]

  float* out      = (float*)d_out;              // [4,2048,1024]
  float* attn_vec = out + (size_t)BT * HIDDEN;  // [4,16,2048,64]

  // Workspace layout. x_bf/w_bf are dead after the QKV GEMM; the partial
  // buffers (written by attn_partial, later) overlap them.
  short* qkv_bf  = (short*)d_ws;                           // [8192][2112] bf16
  short* vt_bf   = qkv_bf + (size_t)BT * QKV_OUT;          // [4][64][2048] bf16
  short* wout_bf = vt_bf + (size_t)BATCH * DHEAD * TSEQ;   // [1024][64] bf16
  short* m_attn  = wout_bf + (size_t)HIDDEN * DHEAD;       // [8192][64] bf16
  char*  xbase   = (char*)(m_attn + (size_t)BT * DHEAD);
  short* x_bf    = (short*)xbase;                          // [8192][1024] bf16
  short* w_bf    = x_bf + (size_t)BT * HIDDEN;             // [2112][1024] bf16
  float* pO      = (float*)xbase;                          // [64*72][64][64] f32
  float* pL      = pO + (size_t)64 * 72 * 4096;            // [64*72][64] f32

  // 0. convert inputs to bf16
  f32_to_bf16<<<dim3(BT * HIDDEN / 8 / 256), 256, 0, stream>>>(
      x, x_bf, BT * HIDDEN);
  f32_to_bf16<<<dim3(QKV_OUT * HIDDEN / 8 / 256), 256, 0, stream>>>(
      w_qkv, w_bf, QKV_OUT * HIDDEN);
  f32_to_bf16<<<dim3(HIDDEN * DHEAD / 8 / 256), 256, 0, stream>>>(
      w_out, wout_bf, HIDDEN * DHEAD);

  // 1. qkv = x @ w_qkv^T + b_qkv  (bf16 MFMA, fp32 acc, bf16 out)
  gemm_mfma_bf16<short><<<dim3(QKV_OUT / QK_BN, BT / QK_BM), 256, 0, stream>>>(
      x_bf, w_bf, b_qkv, qkv_bf, BT, QKV_OUT, HIDDEN);

  // 2. pre-transpose V: vt[b][d][t]
  transpose_v<<<dim3(TSEQ / 64, BATCH), 256, 0, stream>>>(qkv_bf, vt_bf);

  // 3. split-j MFMA causal flash attention (80 (it,jc) pairs, zero-barrier)
  attn_partial<<<dim3(80, NHEAD, BATCH), 256, 0, stream>>>(
      qkv_bf, vt_bf, attn_vec, pO, pL);

  // 3b. combine partials for it>=8
  attn_combine<<<dim3(24, NHEAD, BATCH), 256, 0, stream>>>(pO, pL, attn_vec);

  // 4. mean over heads -> bf16
  mean_heads<<<dim3(BT * DHEAD / 2 / 256), 256, 0, stream>>>(attn_vec, m_attn);

  // 5. out = m_attn @ w_out^T + b_out  (bf16 MFMA, fp32 out)
  gemm_mfma_bf16<float><<<dim3(HIDDEN / QK_BN, BT / QK_BM), 256, 0, stream>>>(
      m_attn, wout_bf, b_out, out, BT, HIDDEN, DHEAD);
}

// Round 6
// 286.447 us; speedup vs baseline: 1.6710x; 1.6710x over previous
//
#include <hip/hip_runtime.h>
#include <hip/hip_bf16.h>
#include <math.h>

// Problem constants
#define NHEAD 16
#define DHEAD 64
#define HIDDEN 1024
#define TSEQ 2048
#define BATCH 4
#define QKV_OUT 2112   // (2*16+1)*64
#define BT (BATCH * TSEQ)  // 8192

typedef __attribute__((ext_vector_type(8))) short bf16x8;
typedef __attribute__((ext_vector_type(4))) float floatx4;

static __device__ __forceinline__ short f2bf(float x) {
  __hip_bfloat16 h = __float2bfloat16(x);
  return *reinterpret_cast<short*>(&h);
}

#define MFMA16(a, b, c) __builtin_amdgcn_mfma_f32_16x16x32_bf16(a, b, c, 0, 0, 0)

// ---------------------------------------------------------------------------
// fp32 -> bf16 conversion, 8 elems/thread. n must be divisible by 8.
// ---------------------------------------------------------------------------
__global__ __launch_bounds__(256) void f32_to_bf16(
    const float* __restrict__ src, short* __restrict__ dst, int n) {
  const int i = (blockIdx.x * 256 + threadIdx.x) * 8;
  if (i >= n) return;
  float4 a = *(const float4*)&src[i];
  float4 b = *(const float4*)&src[i + 4];
  short o[8];
  o[0] = f2bf(a.x); o[1] = f2bf(a.y); o[2] = f2bf(a.z); o[3] = f2bf(a.w);
  o[4] = f2bf(b.x); o[5] = f2bf(b.y); o[6] = f2bf(b.z); o[7] = f2bf(b.w);
  *(uint4*)&dst[i] = *(uint4*)o;
}

// ---------------------------------------------------------------------------
// MFMA bf16 GEMM: C[M][N] = A[M][K] @ B[N][K]^T + bias[N].
// BM=128, BN=64, BK=64; 4 waves 2x2; wave tile 64x32. Pad 72 shorts/row.
// T14 async-stage split: next K-tile's global loads are issued AFTER the
// compute-entry barrier so their ~500cy latency drains under the MFMAs
// (round-0 issued them right before the barrier -> latency exposed).
// Tile stays 128x64 / acc[4][2]: the 128x128 acc[4][4] variant spilled
// (round 2: 515 MB scratch writes). ~80 VGPR here, no spill expected.
// ---------------------------------------------------------------------------
#define QK_BM 128
#define QK_BN 64
#define QK_BK 64

template <typename OUT_T>
__global__ __launch_bounds__(256) void gemm_mfma_bf16(
    const short* __restrict__ A, const short* __restrict__ B,
    const float* __restrict__ bias, OUT_T* __restrict__ C,
    int M, int N, int K) {
  __shared__ short As[QK_BM][72];
  __shared__ short Bs[QK_BN][72];

  const int tid = threadIdx.x;
  const int lane = tid & 63;
  const int wv = tid >> 6;
  const int ln = lane & 15;
  const int grp = lane >> 4;
  const int wm = wv >> 1;
  const int wn = wv & 1;
  const int rowbase = blockIdx.y * QK_BM;
  const int colbase = blockIdx.x * QK_BN;

  const int ar = tid >> 1, ac = (tid & 1) * 32;
  const int br = tid >> 2, bc = (tid & 3) * 16;

  floatx4 acc[4][2];
#pragma unroll
  for (int m = 0; m < 4; ++m)
#pragma unroll
    for (int n = 0; n < 2; ++n) acc[m][n] = (floatx4){0.f, 0.f, 0.f, 0.f};

  const short* ap = A + (size_t)(rowbase + ar) * K + ac;
  const short* bp = B + (size_t)(colbase + br) * K + bc;

  // prologue: K-tile 0 into registers
  uint4 a0 = *(const uint4*)(ap + 0);
  uint4 a1 = *(const uint4*)(ap + 8);
  uint4 a2 = *(const uint4*)(ap + 16);
  uint4 a3 = *(const uint4*)(ap + 24);
  uint4 b0 = *(const uint4*)(bp + 0);
  uint4 b1 = *(const uint4*)(bp + 8);

  for (int k0 = 0; k0 < K; k0 += QK_BK) {
    __syncthreads();  // previous iteration's LDS reads done
    *(uint4*)&As[ar][ac + 0] = a0;
    *(uint4*)&As[ar][ac + 8] = a1;
    *(uint4*)&As[ar][ac + 16] = a2;
    *(uint4*)&As[ar][ac + 24] = a3;
    *(uint4*)&Bs[br][bc + 0] = b0;
    *(uint4*)&Bs[br][bc + 8] = b1;
    __syncthreads();

    // issue next K-tile loads now; they drain under the MFMAs below
    if (k0 + QK_BK < K) {
      ap += QK_BK;
      bp += QK_BK;
      a0 = *(const uint4*)(ap + 0);
      a1 = *(const uint4*)(ap + 8);
      a2 = *(const uint4*)(ap + 16);
      a3 = *(const uint4*)(ap + 24);
      b0 = *(const uint4*)(bp + 0);
      b1 = *(const uint4*)(bp + 8);
    }

#pragma unroll
    for (int ks = 0; ks < 2; ++ks) {
      bf16x8 bfrag[2];
#pragma unroll
      for (int n = 0; n < 2; ++n)
        bfrag[n] = *(const bf16x8*)&Bs[wn * 32 + n * 16 + ln][ks * 32 + grp * 8];
#pragma unroll
      for (int m = 0; m < 4; ++m) {
        bf16x8 af = *(const bf16x8*)&As[wm * 64 + m * 16 + ln][ks * 32 + grp * 8];
#pragma unroll
        for (int n = 0; n < 2; ++n)
          acc[m][n] = MFMA16(af, bfrag[n], acc[m][n]);
      }
    }
  }

#pragma unroll
  for (int n = 0; n < 2; ++n) {
    const int col = colbase + wn * 32 + n * 16 + ln;
    const float bv = bias[col];
#pragma unroll
    for (int m = 0; m < 4; ++m) {
#pragma unroll
      for (int r = 0; r < 4; ++r) {
        const int row = rowbase + wm * 64 + m * 16 + grp * 4 + r;
        const float v = acc[m][n][r] + bv;
        if constexpr (sizeof(OUT_T) == 2)
          C[(size_t)row * N + col] = f2bf(v);
        else
          C[(size_t)row * N + col] = v;
      }
    }
  }
}

// ---------------------------------------------------------------------------
// Transpose V: vt[b][d][t] = qkv_bf16[b*T + t][2048 + d]
// ---------------------------------------------------------------------------
__global__ __launch_bounds__(256) void transpose_v(
    const short* __restrict__ qkv, short* __restrict__ vt) {
  __shared__ short tile[64][72];
  const int tt = blockIdx.x;
  const int b = blockIdx.y;
  const int tid = threadIdx.x;
  const int li = tid >> 2;
  const int lc = (tid & 3) * 16;

  const short* src = qkv + (size_t)(b * TSEQ + tt * 64 + li) * QKV_OUT + 2048 + lc;
  *(uint4*)&tile[li][lc] = *(const uint4*)src;
  *(uint4*)&tile[li][lc + 8] = *(const uint4*)(src + 8);
  __syncthreads();
  short tmp[16];
#pragma unroll
  for (int u = 0; u < 16; ++u) tmp[u] = tile[lc + u][li];
  short* dst = vt + (size_t)(b * 64 + li) * TSEQ + tt * 64 + lc;
  *(uint4*)dst = *(uint4*)&tmp[0];
  *(uint4*)(dst + 8) = *(uint4*)&tmp[8];
}

// ---------------------------------------------------------------------------
// Split-j MFMA bf16 causal flash attention (round-0 verified structure:
// single-buffer cooperative LDS staging, 2 barriers/tile, next-tile global
// prefetch in regs). ONLY change vs round 0: s_setprio(1) around the two
// MFMA clusters (T5: resident blocks sit at different j-phases, so raising
// MFMA-wave priority keeps the matrix pipe fed while other waves stage).
// Block = ((it,jc), h, b): 64 q-rows, <=8 j-tiles.
// it<8 (single chunk): write normalized attn_vec directly.
// it>=8: write unnormalized O^T (fp32) + l to partial workspace.
// ---------------------------------------------------------------------------
#define CH 8  // j-tiles per chunk

__global__ __launch_bounds__(256) void attn_partial(
    const short* __restrict__ qkv, const short* __restrict__ vt,
    float* __restrict__ attn_vec, float* __restrict__ pO,
    float* __restrict__ pL) {
  __shared__ short Ks[64][72];  // [j][d]
  __shared__ short Vt[64][72];  // [d][j]
  __shared__ short Ps[64][72];  // [q][j], per-wave 16-row slices

  const int x = gridDim.x - 1 - blockIdx.x;  // big-it blocks dispatch first
  int it, jc;
  if (x < 8) {
    it = x; jc = 0;
  } else if (x < 24) {
    it = 8 + ((x - 8) >> 1); jc = (x - 8) & 1;
  } else if (x < 48) {
    it = 16 + (x - 24) / 3; jc = (x - 24) % 3;
  } else {
    it = 24 + ((x - 48) >> 2); jc = (x - 48) & 3;
  }
  const int jstart = jc * CH;
  const int jend = min(jstart + CH, it + 1);

  const int tid = threadIdx.x;
  const int h = blockIdx.y;
  const int b = blockIdx.z;
  const int lane = tid & 63;
  const int wv = tid >> 6;
  const int ln = lane & 15;
  const int grp = lane >> 4;
  const int qbase = wv * 16;
  const int sli = tid & 63;
  const int slc = (tid >> 6) * 16;
  const float CEXP = 0.18033688f;  // 0.125 * log2(e)

  // Q B-fragment (persistent): B[k=d][n=q]
  const short* qptr = qkv + (size_t)(b * TSEQ + it * 64 + qbase + ln) * QKV_OUT + h * 64;
  const bf16x8 bq0 = *(const bf16x8*)(qptr + grp * 8);
  const bf16x8 bq1 = *(const bf16x8*)(qptr + 32 + grp * 8);

  floatx4 oT[4];
#pragma unroll
  for (int m = 0; m < 4; ++m) oT[m] = (floatx4){0.f, 0.f, 0.f, 0.f};
  float lsum = 0.f;

  // prefetch first tile of this chunk
  const short* ks0 = qkv + (size_t)(b * TSEQ + jstart * 64 + sli) * QKV_OUT + 1024 + h * 64 + slc;
  const short* vs0 = vt + (size_t)(b * 64 + sli) * TSEQ + jstart * 64 + slc;
  uint4 kr0 = *(const uint4*)ks0;
  uint4 kr1 = *(const uint4*)(ks0 + 8);
  uint4 vr0 = *(const uint4*)vs0;
  uint4 vr1 = *(const uint4*)(vs0 + 8);

  for (int jt = jstart; jt < jend; ++jt) {
    __syncthreads();  // all waves done reading previous Ks/Vt
    *(uint4*)&Ks[sli][slc] = kr0;
    *(uint4*)&Ks[sli][slc + 8] = kr1;
    *(uint4*)&Vt[sli][slc] = vr0;
    *(uint4*)&Vt[sli][slc + 8] = vr1;
    __syncthreads();

    // prefetch next tile (latency hidden under compute)
    if (jt + 1 < jend) {
      const short* kn =
          qkv + (size_t)(b * TSEQ + (jt + 1) * 64 + sli) * QKV_OUT + 1024 + h * 64 + slc;
      const short* vn = vt + (size_t)(b * 64 + sli) * TSEQ + (jt + 1) * 64 + slc;
      kr0 = *(const uint4*)kn;
      kr1 = *(const uint4*)(kn + 8);
      vr0 = *(const uint4*)vn;
      vr1 = *(const uint4*)(vn + 8);
    }

    // S^T = K @ Q^T: 4 m-tiles (j), 2 k-steps (d)
    floatx4 st[4];
    __builtin_amdgcn_s_setprio(1);
#pragma unroll
    for (int m = 0; m < 4; ++m) {
      bf16x8 ak0 = *(const bf16x8*)&Ks[m * 16 + ln][grp * 8];
      bf16x8 ak1 = *(const bf16x8*)&Ks[m * 16 + ln][32 + grp * 8];
      floatx4 a = (floatx4){0.f, 0.f, 0.f, 0.f};
      a = MFMA16(ak0, bq0, a);
      a = MFMA16(ak1, bq1, a);
      st[m] = a;
    }
    __builtin_amdgcn_s_setprio(0);

    // causal mask on diagonal tile: j-local > q-local -> -inf
    if (jt == it) {
#pragma unroll
      for (int m = 0; m < 4; ++m)
#pragma unroll
        for (int r = 0; r < 4; ++r)
          if (m * 16 + grp * 4 + r > qbase + ln) st[m][r] = -INFINITY;
    }

    // P = exp2(CEXP * s), accumulate l, packed bf16x4 store to Ps
#pragma unroll
    for (int m = 0; m < 4; ++m) {
      float p0 = exp2f(CEXP * st[m][0]);
      float p1 = exp2f(CEXP * st[m][1]);
      float p2 = exp2f(CEXP * st[m][2]);
      float p3 = exp2f(CEXP * st[m][3]);
      lsum += (p0 + p1) + (p2 + p3);
      short pk[4] = {f2bf(p0), f2bf(p1), f2bf(p2), f2bf(p3)};
      *(uint2*)&Ps[qbase + ln][m * 16 + grp * 4] = *(uint2*)pk;
    }

    // O^T += V^T(A) @ P^T(B)  (same-wave LDS write->read, in-order DS)
    bf16x8 bp0 = *(const bf16x8*)&Ps[qbase + ln][grp * 8];
    bf16x8 bp1 = *(const bf16x8*)&Ps[qbase + ln][32 + grp * 8];
    __builtin_amdgcn_s_setprio(1);
#pragma unroll
    for (int m = 0; m < 4; ++m) {
      bf16x8 av0 = *(const bf16x8*)&Vt[m * 16 + ln][grp * 8];
      bf16x8 av1 = *(const bf16x8*)&Vt[m * 16 + ln][32 + grp * 8];
      oT[m] = MFMA16(av0, bp0, oT[m]);
      oT[m] = MFMA16(av1, bp1, oT[m]);
    }
    __builtin_amdgcn_s_setprio(0);
  }

  // reduce l across grp (lanes with same ln share q)
  lsum += __shfl_xor(lsum, 16);
  lsum += __shfl_xor(lsum, 32);

  if (it < 8) {
    // single chunk: normalize and write attn_vec directly
    const float inv = 1.f / lsum;
    float* orow =
        attn_vec + ((size_t)(b * NHEAD + h) * TSEQ + it * 64 + qbase + ln) * DHEAD;
#pragma unroll
    for (int m = 0; m < 4; ++m) {
      float4 o4;
      o4.x = oT[m][0] * inv;
      o4.y = oT[m][1] * inv;
      o4.z = oT[m][2] * inv;
      o4.w = oT[m][3] * inv;
      *(float4*)&orow[m * 16 + grp * 4] = o4;
    }
  } else {
    // write unnormalized partial
    const int slot = (it < 16) ? (it - 8) * 2 + jc
                   : (it < 24) ? 16 + (it - 16) * 3 + jc
                               : 40 + (it - 24) * 4 + jc;
    const size_t sbase = (size_t)(b * NHEAD + h) * 72 + slot;
    float* prow = pO + sbase * 4096 + (size_t)(qbase + ln) * 64;
#pragma unroll
    for (int m = 0; m < 4; ++m) {
      float4 o4;
      o4.x = oT[m][0]; o4.y = oT[m][1]; o4.z = oT[m][2]; o4.w = oT[m][3];
      *(float4*)&prow[m * 16 + grp * 4] = o4;
    }
    if (grp == 0) pL[sbase * 64 + qbase + ln] = lsum;
  }
}

// ---------------------------------------------------------------------------
// Combine partials for it>=8: sum O^T chunks + l, normalize, write attn_vec.
// Block = (it-8, h, b); thread -> q = tid>>2, 16 d-cols.
// ---------------------------------------------------------------------------
__global__ __launch_bounds__(256) void attn_combine(
    const float* __restrict__ pO, const float* __restrict__ pL,
    float* __restrict__ attn_vec) {
  const int it = 8 + blockIdx.x;  // 8..31
  const int h = blockIdx.y;
  const int b = blockIdx.z;
  const int nch = (it < 16) ? 2 : (it < 24) ? 3 : 4;
  const int slot0 = (it < 16) ? (it - 8) * 2
                  : (it < 24) ? 16 + (it - 16) * 3
                              : 40 + (it - 24) * 4;
  const int q = threadIdx.x >> 2;
  const int dbase = (threadIdx.x & 3) * 16;
  const size_t base = (size_t)(b * NHEAD + h) * 72 + slot0;

  float4 acc[4];
#pragma unroll
  for (int u = 0; u < 4; ++u) acc[u] = (float4){0.f, 0.f, 0.f, 0.f};
  float l = 0.f;
  for (int c = 0; c < nch; ++c) {
    const float* pr = pO + (base + c) * 4096 + (size_t)q * 64 + dbase;
#pragma unroll
    for (int u = 0; u < 4; ++u) {
      float4 v = *(const float4*)&pr[u * 4];
      acc[u].x += v.x; acc[u].y += v.y; acc[u].z += v.z; acc[u].w += v.w;
    }
    l += pL[(base + c) * 64 + q];
  }
  const float inv = 1.f / l;
  float* orow =
      attn_vec + ((size_t)(b * NHEAD + h) * TSEQ + it * 64 + q) * DHEAD + dbase;
#pragma unroll
  for (int u = 0; u < 4; ++u) {
    float4 o4;
    o4.x = acc[u].x * inv; o4.y = acc[u].y * inv;
    o4.z = acc[u].z * inv; o4.w = acc[u].w * inv;
    *(float4*)&orow[u * 4] = o4;
  }
}

// ---------------------------------------------------------------------------
// Mean over heads -> bf16 (feeds the MFMA out-projection). 2 elems/thread.
// ---------------------------------------------------------------------------
__global__ __launch_bounds__(256) void mean_heads(
    const float* __restrict__ attn_vec, short* __restrict__ m) {
  const int gid = blockIdx.x * 256 + threadIdx.x;  // over BT*64/2
  const int d2 = (gid & 31) * 2;
  const int t = (gid >> 5) & (TSEQ - 1);
  const int b = gid >> 16;
  float s0 = 0.f, s1 = 0.f;
#pragma unroll
  for (int h = 0; h < NHEAD; ++h) {
    const float* p = &attn_vec[(((size_t)(b * NHEAD + h) * TSEQ) + t) * DHEAD + d2];
    s0 += p[0];
    s1 += p[1];
  }
  short pk[2] = {f2bf(s0 * (1.f / 16.f)), f2bf(s1 * (1.f / 16.f))};
  *(uint*)&m[gid * 2] = *(uint*)pk;
}

// ---------------------------------------------------------------------------
extern "C" void kernel_launch(void* const* d_in, const int* in_sizes, int n_in,
                              void* d_out, int out_size, void* d_ws, size_t ws_size,
                              hipStream_t stream) {
  const float* x     = (const float*)d_in[0];  // [4,2048,1024]
  const float* w_qkv = (const float*)d_in[1];  // [2112,1024]
  const float* b_qkv = (const float*)d_in[2];  // [2112]
  const float* w_out = (const float*)d_in[3];  // [1024,64]
  const float* b_out = (const float*)d_in[4];  // [1024]

  float* out      = (float*)d_out;              // [4,2048,1024]
  float* attn_vec = out + (size_t)BT * HIDDEN;  // [4,16,2048,64]

  // Workspace layout. x_bf/w_bf are dead after the QKV GEMM; the partial
  // buffers (written by attn_partial, later) overlap them.
  short* qkv_bf  = (short*)d_ws;                           // [8192][2112] bf16
  short* vt_bf   = qkv_bf + (size_t)BT * QKV_OUT;          // [4][64][2048] bf16
  short* wout_bf = vt_bf + (size_t)BATCH * DHEAD * TSEQ;   // [1024][64] bf16
  short* m_attn  = wout_bf + (size_t)HIDDEN * DHEAD;       // [8192][64] bf16
  char*  xbase   = (char*)(m_attn + (size_t)BT * DHEAD);
  short* x_bf    = (short*)xbase;                          // [8192][1024] bf16
  short* w_bf    = x_bf + (size_t)BT * HIDDEN;             // [2112][1024] bf16
  float* pO      = (float*)xbase;                          // [64*72][64][64] f32
  float* pL      = pO + (size_t)64 * 72 * 4096;            // [64*72][64] f32

  // 0. convert inputs to bf16
  f32_to_bf16<<<dim3(BT * HIDDEN / 8 / 256), 256, 0, stream>>>(
      x, x_bf, BT * HIDDEN);
  f32_to_bf16<<<dim3(QKV_OUT * HIDDEN / 8 / 256), 256, 0, stream>>>(
      w_qkv, w_bf, QKV_OUT * HIDDEN);
  f32_to_bf16<<<dim3(HIDDEN * DHEAD / 8 / 256), 256, 0, stream>>>(
      w_out, wout_bf, HIDDEN * DHEAD);

  // 1. qkv = x @ w_qkv^T + b_qkv  (bf16 MFMA, fp32 acc, bf16 out)
  gemm_mfma_bf16<short><<<dim3(QKV_OUT / QK_BN, BT / QK_BM), 256, 0, stream>>>(
      x_bf, w_bf, b_qkv, qkv_bf, BT, QKV_OUT, HIDDEN);

  // 2. pre-transpose V: vt[b][d][t]
  transpose_v<<<dim3(TSEQ / 64, BATCH), 256, 0, stream>>>(qkv_bf, vt_bf);

  // 3. split-j MFMA causal flash attention (80 (it,jc) pairs)
  attn_partial<<<dim3(80, NHEAD, BATCH), 256, 0, stream>>>(
      qkv_bf, vt_bf, attn_vec, pO, pL);

  // 3b. combine partials for it>=8
  attn_combine<<<dim3(24, NHEAD, BATCH), 256, 0, stream>>>(pO, pL, attn_vec);

  // 4. mean over heads -> bf16
  mean_heads<<<dim3(BT * DHEAD / 2 / 256), 256, 0, stream>>>(attn_vec, m_attn);

  // 5. out = m_attn @ w_out^T + b_out  (bf16 MFMA, fp32 out)
  gemm_mfma_bf16<float><<<dim3(HIDDEN / QK_BN, BT / QK_BM), 256, 0, stream>>>(
      m_attn, wout_bf, b_out, out, BT, HIDDEN, DHEAD);
}

// Round 7
// 285.474 us; speedup vs baseline: 1.6767x; 1.0034x over previous
//
#include <hip/hip_runtime.h>
#include <hip/hip_bf16.h>
#include <math.h>

// Problem constants
#define NHEAD 16
#define DHEAD 64
#define HIDDEN 1024
#define TSEQ 2048
#define BATCH 4
#define QKV_OUT 2112   // (2*16+1)*64
#define BT (BATCH * TSEQ)  // 8192

typedef __attribute__((ext_vector_type(8))) short bf16x8;
typedef __attribute__((ext_vector_type(4))) float floatx4;

static __device__ __forceinline__ short f2bf(float x) {
  __hip_bfloat16 h = __float2bfloat16(x);
  return *reinterpret_cast<short*>(&h);
}

#define MFMA16(a, b, c) __builtin_amdgcn_mfma_f32_16x16x32_bf16(a, b, c, 0, 0, 0)

// ---------------------------------------------------------------------------
// fp32 -> bf16 conversion, 8 elems/thread. n must be divisible by 8.
// ---------------------------------------------------------------------------
__global__ __launch_bounds__(256) void f32_to_bf16(
    const float* __restrict__ src, short* __restrict__ dst, int n) {
  const int i = (blockIdx.x * 256 + threadIdx.x) * 8;
  if (i >= n) return;
  float4 a = *(const float4*)&src[i];
  float4 b = *(const float4*)&src[i + 4];
  short o[8];
  o[0] = f2bf(a.x); o[1] = f2bf(a.y); o[2] = f2bf(a.z); o[3] = f2bf(a.w);
  o[4] = f2bf(b.x); o[5] = f2bf(b.y); o[6] = f2bf(b.z); o[7] = f2bf(b.w);
  *(uint4*)&dst[i] = *(uint4*)o;
}

// ---------------------------------------------------------------------------
// MFMA bf16 GEMM: C[M][N] = A[M][K] @ B[N][K]^T + bias[N].
// BM=128, BN=64, BK=64; 4 waves 2x2; wave tile 64x32. Pad 72 shorts/row.
// (Verified structure; rounds 1/2 showed 128x128 variants regress/spill.)
// ---------------------------------------------------------------------------
#define QK_BM 128
#define QK_BN 64
#define QK_BK 64

template <typename OUT_T>
__global__ __launch_bounds__(256) void gemm_mfma_bf16(
    const short* __restrict__ A, const short* __restrict__ B,
    const float* __restrict__ bias, OUT_T* __restrict__ C,
    int M, int N, int K) {
  __shared__ short As[QK_BM][72];
  __shared__ short Bs[QK_BN][72];

  const int tid = threadIdx.x;
  const int lane = tid & 63;
  const int wv = tid >> 6;
  const int ln = lane & 15;
  const int grp = lane >> 4;
  const int wm = wv >> 1;
  const int wn = wv & 1;
  const int rowbase = blockIdx.y * QK_BM;
  const int colbase = blockIdx.x * QK_BN;

  const int ar = tid >> 1, ac = (tid & 1) * 32;
  const int br = tid >> 2, bc = (tid & 3) * 16;

  floatx4 acc[4][2];
#pragma unroll
  for (int m = 0; m < 4; ++m)
#pragma unroll
    for (int n = 0; n < 2; ++n) acc[m][n] = (floatx4){0.f, 0.f, 0.f, 0.f};

  const short* ap = A + (size_t)(rowbase + ar) * K + ac;
  const short* bp = B + (size_t)(colbase + br) * K + bc;

  // prologue: K-tile 0 into registers
  uint4 a0 = *(const uint4*)(ap + 0);
  uint4 a1 = *(const uint4*)(ap + 8);
  uint4 a2 = *(const uint4*)(ap + 16);
  uint4 a3 = *(const uint4*)(ap + 24);
  uint4 b0 = *(const uint4*)(bp + 0);
  uint4 b1 = *(const uint4*)(bp + 8);

  for (int k0 = 0; k0 < K; k0 += QK_BK) {
    __syncthreads();  // previous iteration's LDS reads done
    *(uint4*)&As[ar][ac + 0] = a0;
    *(uint4*)&As[ar][ac + 8] = a1;
    *(uint4*)&As[ar][ac + 16] = a2;
    *(uint4*)&As[ar][ac + 24] = a3;
    *(uint4*)&Bs[br][bc + 0] = b0;
    *(uint4*)&Bs[br][bc + 8] = b1;
    __syncthreads();

    // issue next K-tile loads now; they drain under the MFMAs below
    if (k0 + QK_BK < K) {
      ap += QK_BK;
      bp += QK_BK;
      a0 = *(const uint4*)(ap + 0);
      a1 = *(const uint4*)(ap + 8);
      a2 = *(const uint4*)(ap + 16);
      a3 = *(const uint4*)(ap + 24);
      b0 = *(const uint4*)(bp + 0);
      b1 = *(const uint4*)(bp + 8);
    }

#pragma unroll
    for (int ks = 0; ks < 2; ++ks) {
      bf16x8 bfrag[2];
#pragma unroll
      for (int n = 0; n < 2; ++n)
        bfrag[n] = *(const bf16x8*)&Bs[wn * 32 + n * 16 + ln][ks * 32 + grp * 8];
#pragma unroll
      for (int m = 0; m < 4; ++m) {
        bf16x8 af = *(const bf16x8*)&As[wm * 64 + m * 16 + ln][ks * 32 + grp * 8];
#pragma unroll
        for (int n = 0; n < 2; ++n)
          acc[m][n] = MFMA16(af, bfrag[n], acc[m][n]);
      }
    }
  }

#pragma unroll
  for (int n = 0; n < 2; ++n) {
    const int col = colbase + wn * 32 + n * 16 + ln;
    const float bv = bias[col];
#pragma unroll
    for (int m = 0; m < 4; ++m) {
#pragma unroll
      for (int r = 0; r < 4; ++r) {
        const int row = rowbase + wm * 64 + m * 16 + grp * 4 + r;
        const float v = acc[m][n][r] + bv;
        if constexpr (sizeof(OUT_T) == 2)
          C[(size_t)row * N + col] = f2bf(v);
        else
          C[(size_t)row * N + col] = v;
      }
    }
  }
}

// ---------------------------------------------------------------------------
// Transpose V: vt[b][d][t] = qkv_bf16[b*T + t][2048 + d]
// ---------------------------------------------------------------------------
__global__ __launch_bounds__(256) void transpose_v(
    const short* __restrict__ qkv, short* __restrict__ vt) {
  __shared__ short tile[64][72];
  const int tt = blockIdx.x;
  const int b = blockIdx.y;
  const int tid = threadIdx.x;
  const int li = tid >> 2;
  const int lc = (tid & 3) * 16;

  const short* src = qkv + (size_t)(b * TSEQ + tt * 64 + li) * QKV_OUT + 2048 + lc;
  *(uint4*)&tile[li][lc] = *(const uint4*)src;
  *(uint4*)&tile[li][lc + 8] = *(const uint4*)(src + 8);
  __syncthreads();
  short tmp[16];
#pragma unroll
  for (int u = 0; u < 16; ++u) tmp[u] = tile[lc + u][li];
  short* dst = vt + (size_t)(b * 64 + li) * TSEQ + tt * 64 + lc;
  *(uint4*)dst = *(uint4*)&tmp[0];
  *(uint4*)(dst + 8) = *(uint4*)&tmp[8];
}

// ---------------------------------------------------------------------------
// Split-j MFMA bf16 causal flash attention, QB=128 / 8-wave variant.
// Same per-wave inner loop as the verified round-0 kernel; the ONLY
// structural change: each staged 64x64 K/V tile now feeds 8 waves
// (128 q-rows) instead of 4 -> staged bytes + barrier-pairs per unit of
// work halve (528 -> 272 tile-stagings per (b,h)). Chunks are <=16
// j-tiles; it<8 writes attn_vec directly, it>=8 has exactly 2 chunks.
// Waves fully above the diagonal skip compute wave-uniformly (still
// participate in staging + barriers).
// ---------------------------------------------------------------------------
#define QB 128

__global__ __launch_bounds__(512) void attn_partial(
    const short* __restrict__ qkv, const short* __restrict__ vt,
    float* __restrict__ attn_vec, float* __restrict__ pO,
    float* __restrict__ pL) {
  __shared__ short Ks[64][72];   // [j][d]
  __shared__ short Vt[64][72];   // [d][j]
  __shared__ short Ps[128][72];  // [q][j], per-wave 16-row slices

  const int x = (int)gridDim.x - 1 - (int)blockIdx.x;  // big blocks first
  int it, jc;
  if (x < 8) {
    it = x; jc = 0;                       // njt = 2it+2 <= 16: single chunk
  } else {
    it = 8 + ((x - 8) >> 1); jc = (x - 8) & 1;  // it>=8: 2 chunks of <=16
  }
  const int jstart = jc * 16;
  const int jend = min(jstart + 16, 2 * it + 2);

  const int tid = threadIdx.x;  // 0..511
  const int h = blockIdx.y;
  const int b = blockIdx.z;
  const int lane = tid & 63;
  const int wv = tid >> 6;      // 0..7
  const int ln = lane & 15;
  const int grp = lane >> 4;
  const int qbase = wv * 16;    // 0..112: wave's 16 q-rows within the 128
  const int sr = tid >> 3;          // staging row 0..63
  const int sc = (tid & 7) * 8;     // staging col (shorts) 0..56
  const float CEXP = 0.18033688f;   // 0.125 * log2(e)

  // Q B-fragment (persistent): B[k=d][n=q]
  const short* qptr =
      qkv + (size_t)(b * TSEQ + it * QB + qbase + ln) * QKV_OUT + h * 64;
  const bf16x8 bq0 = *(const bf16x8*)(qptr + grp * 8);
  const bf16x8 bq1 = *(const bf16x8*)(qptr + 32 + grp * 8);

  floatx4 oT[4];
#pragma unroll
  for (int m = 0; m < 4; ++m) oT[m] = (floatx4){0.f, 0.f, 0.f, 0.f};
  float lsum = 0.f;

  // prefetch first tile of this chunk (1 uint4 K + 1 uint4 V per thread)
  const short* ks0 =
      qkv + (size_t)(b * TSEQ + jstart * 64 + sr) * QKV_OUT + 1024 + h * 64 + sc;
  const short* vs0 = vt + (size_t)(b * 64 + sr) * TSEQ + jstart * 64 + sc;
  uint4 kr = *(const uint4*)ks0;
  uint4 vr = *(const uint4*)vs0;

  for (int jt = jstart; jt < jend; ++jt) {
    __syncthreads();  // all waves done reading previous Ks/Vt
    *(uint4*)&Ks[sr][sc] = kr;
    *(uint4*)&Vt[sr][sc] = vr;
    __syncthreads();

    // prefetch next tile (latency hidden under compute)
    if (jt + 1 < jend) {
      const short* kn =
          qkv + (size_t)(b * TSEQ + (jt + 1) * 64 + sr) * QKV_OUT + 1024 + h * 64 + sc;
      const short* vn = vt + (size_t)(b * 64 + sr) * TSEQ + (jt + 1) * 64 + sc;
      kr = *(const uint4*)kn;
      vr = *(const uint4*)vn;
    }

    // wave-uniform skip: this wave's q-rows all above the diagonal?
    const int qg = it * QB + qbase;  // wave's lowest q-row
    if (qg + 15 >= jt * 64) {
      // S^T = K @ Q^T: 4 m-tiles (j), 2 k-steps (d)
      floatx4 st[4];
      __builtin_amdgcn_s_setprio(1);
#pragma unroll
      for (int m = 0; m < 4; ++m) {
        bf16x8 ak0 = *(const bf16x8*)&Ks[m * 16 + ln][grp * 8];
        bf16x8 ak1 = *(const bf16x8*)&Ks[m * 16 + ln][32 + grp * 8];
        floatx4 a = (floatx4){0.f, 0.f, 0.f, 0.f};
        a = MFMA16(ak0, bq0, a);
        a = MFMA16(ak1, bq1, a);
        st[m] = a;
      }
      __builtin_amdgcn_s_setprio(0);

      // causal mask: j-elements above this lane's q-row -> -inf
      const int dj = qg + ln - jt * 64;  // elements j_local > dj are masked
      if (dj < 63) {
#pragma unroll
        for (int m = 0; m < 4; ++m)
#pragma unroll
          for (int r = 0; r < 4; ++r)
            if (m * 16 + grp * 4 + r > dj) st[m][r] = -INFINITY;
      }

      // P = exp2(CEXP * s), accumulate l, packed bf16x4 store to Ps
#pragma unroll
      for (int m = 0; m < 4; ++m) {
        float p0 = exp2f(CEXP * st[m][0]);
        float p1 = exp2f(CEXP * st[m][1]);
        float p2 = exp2f(CEXP * st[m][2]);
        float p3 = exp2f(CEXP * st[m][3]);
        lsum += (p0 + p1) + (p2 + p3);
        short pk[4] = {f2bf(p0), f2bf(p1), f2bf(p2), f2bf(p3)};
        *(uint2*)&Ps[qbase + ln][m * 16 + grp * 4] = *(uint2*)pk;
      }

      // O^T += V^T(A) @ P^T(B)  (same-wave LDS write->read, in-order DS)
      bf16x8 bp0 = *(const bf16x8*)&Ps[qbase + ln][grp * 8];
      bf16x8 bp1 = *(const bf16x8*)&Ps[qbase + ln][32 + grp * 8];
      __builtin_amdgcn_s_setprio(1);
#pragma unroll
      for (int m = 0; m < 4; ++m) {
        bf16x8 av0 = *(const bf16x8*)&Vt[m * 16 + ln][grp * 8];
        bf16x8 av1 = *(const bf16x8*)&Vt[m * 16 + ln][32 + grp * 8];
        oT[m] = MFMA16(av0, bp0, oT[m]);
        oT[m] = MFMA16(av1, bp1, oT[m]);
      }
      __builtin_amdgcn_s_setprio(0);
    }
  }

  // reduce l across grp (lanes with same ln share q)
  lsum += __shfl_xor(lsum, 16);
  lsum += __shfl_xor(lsum, 32);

  if (it < 8) {
    // single chunk: normalize and write attn_vec directly
    const float inv = 1.f / lsum;
    float* orow =
        attn_vec + ((size_t)(b * NHEAD + h) * TSEQ + it * QB + qbase + ln) * DHEAD;
#pragma unroll
    for (int m = 0; m < 4; ++m) {
      float4 o4;
      o4.x = oT[m][0] * inv;
      o4.y = oT[m][1] * inv;
      o4.z = oT[m][2] * inv;
      o4.w = oT[m][3] * inv;
      *(float4*)&orow[m * 16 + grp * 4] = o4;
    }
  } else {
    // write unnormalized partial: slot = (it-8)*2 + jc, 16 slots per (b,h)
    const int slot = (it - 8) * 2 + jc;
    const size_t sbase = (size_t)(b * NHEAD + h) * 16 + slot;
    float* prow = pO + sbase * 8192 + (size_t)(qbase + ln) * 64;
#pragma unroll
    for (int m = 0; m < 4; ++m) {
      float4 o4;
      o4.x = oT[m][0]; o4.y = oT[m][1]; o4.z = oT[m][2]; o4.w = oT[m][3];
      *(float4*)&prow[m * 16 + grp * 4] = o4;
    }
    if (grp == 0) pL[sbase * 128 + qbase + ln] = lsum;
  }
}

// ---------------------------------------------------------------------------
// Combine partials for it>=8: exactly 2 chunks per it. Sum O^T + l,
// normalize, write attn_vec. Block = (it-8, h, b); thread -> q = tid>>1,
// 32 d-cols each.
// ---------------------------------------------------------------------------
__global__ __launch_bounds__(256) void attn_combine(
    const float* __restrict__ pO, const float* __restrict__ pL,
    float* __restrict__ attn_vec) {
  const int it = 8 + blockIdx.x;  // 8..15
  const int h = blockIdx.y;
  const int b = blockIdx.z;
  const int q = threadIdx.x >> 1;           // 0..127
  const int dbase = (threadIdx.x & 1) * 32;
  const size_t base = (size_t)(b * NHEAD + h) * 16 + (it - 8) * 2;

  float4 acc[8];
#pragma unroll
  for (int u = 0; u < 8; ++u) acc[u] = (float4){0.f, 0.f, 0.f, 0.f};
  float l = 0.f;
#pragma unroll
  for (int c = 0; c < 2; ++c) {
    const float* pr = pO + (base + c) * 8192 + (size_t)q * 64 + dbase;
#pragma unroll
    for (int u = 0; u < 8; ++u) {
      float4 v = *(const float4*)&pr[u * 4];
      acc[u].x += v.x; acc[u].y += v.y; acc[u].z += v.z; acc[u].w += v.w;
    }
    l += pL[(base + c) * 128 + q];
  }
  const float inv = 1.f / l;
  float* orow =
      attn_vec + ((size_t)(b * NHEAD + h) * TSEQ + it * QB + q) * DHEAD + dbase;
#pragma unroll
  for (int u = 0; u < 8; ++u) {
    float4 o4;
    o4.x = acc[u].x * inv; o4.y = acc[u].y * inv;
    o4.z = acc[u].z * inv; o4.w = acc[u].w * inv;
    *(float4*)&orow[u * 4] = o4;
  }
}

// ---------------------------------------------------------------------------
// Mean over heads -> bf16 (feeds the MFMA out-projection). 2 elems/thread.
// ---------------------------------------------------------------------------
__global__ __launch_bounds__(256) void mean_heads(
    const float* __restrict__ attn_vec, short* __restrict__ m) {
  const int gid = blockIdx.x * 256 + threadIdx.x;  // over BT*64/2
  const int d2 = (gid & 31) * 2;
  const int t = (gid >> 5) & (TSEQ - 1);
  const int b = gid >> 16;
  float s0 = 0.f, s1 = 0.f;
#pragma unroll
  for (int h = 0; h < NHEAD; ++h) {
    const float* p = &attn_vec[(((size_t)(b * NHEAD + h) * TSEQ) + t) * DHEAD + d2];
    s0 += p[0];
    s1 += p[1];
  }
  short pk[2] = {f2bf(s0 * (1.f / 16.f)), f2bf(s1 * (1.f / 16.f))};
  *(uint*)&m[gid * 2] = *(uint*)pk;
}

// ---------------------------------------------------------------------------
extern "C" void kernel_launch(void* const* d_in, const int* in_sizes, int n_in,
                              void* d_out, int out_size, void* d_ws, size_t ws_size,
                              hipStream_t stream) {
  const float* x     = (const float*)d_in[0];  // [4,2048,1024]
  const float* w_qkv = (const float*)d_in[1];  // [2112,1024]
  const float* b_qkv = (const float*)d_in[2];  // [2112]
  const float* w_out = (const float*)d_in[3];  // [1024,64]
  const float* b_out = (const float*)d_in[4];  // [1024]

  float* out      = (float*)d_out;              // [4,2048,1024]
  float* attn_vec = out + (size_t)BT * HIDDEN;  // [4,16,2048,64]

  // Workspace layout. x_bf/w_bf are dead after the QKV GEMM; the partial
  // buffers (written by attn_partial, later) overlap them.
  short* qkv_bf  = (short*)d_ws;                           // [8192][2112] bf16
  short* vt_bf   = qkv_bf + (size_t)BT * QKV_OUT;          // [4][64][2048] bf16
  short* wout_bf = vt_bf + (size_t)BATCH * DHEAD * TSEQ;   // [1024][64] bf16
  short* m_attn  = wout_bf + (size_t)HIDDEN * DHEAD;       // [8192][64] bf16
  char*  xbase   = (char*)(m_attn + (size_t)BT * DHEAD);
  short* x_bf    = (short*)xbase;                          // [8192][1024] bf16
  short* w_bf    = x_bf + (size_t)BT * HIDDEN;             // [2112][1024] bf16
  float* pO      = (float*)xbase;                          // [64*16][128][64] f32
  float* pL      = pO + (size_t)64 * 16 * 8192;            // [64*16][128] f32

  // 0. convert inputs to bf16
  f32_to_bf16<<<dim3(BT * HIDDEN / 8 / 256), 256, 0, stream>>>(
      x, x_bf, BT * HIDDEN);
  f32_to_bf16<<<dim3(QKV_OUT * HIDDEN / 8 / 256), 256, 0, stream>>>(
      w_qkv, w_bf, QKV_OUT * HIDDEN);
  f32_to_bf16<<<dim3(HIDDEN * DHEAD / 8 / 256), 256, 0, stream>>>(
      w_out, wout_bf, HIDDEN * DHEAD);

  // 1. qkv = x @ w_qkv^T + b_qkv  (bf16 MFMA, fp32 acc, bf16 out)
  gemm_mfma_bf16<short><<<dim3(QKV_OUT / QK_BN, BT / QK_BM), 256, 0, stream>>>(
      x_bf, w_bf, b_qkv, qkv_bf, BT, QKV_OUT, HIDDEN);

  // 2. pre-transpose V: vt[b][d][t]
  transpose_v<<<dim3(TSEQ / 64, BATCH), 256, 0, stream>>>(qkv_bf, vt_bf);

  // 3. split-j MFMA causal flash attention (QB=128, 8 waves, 24 (it,jc) pairs)
  attn_partial<<<dim3(24, NHEAD, BATCH), 512, 0, stream>>>(
      qkv_bf, vt_bf, attn_vec, pO, pL);

  // 3b. combine partials for it>=8 (2 chunks each)
  attn_combine<<<dim3(8, NHEAD, BATCH), 256, 0, stream>>>(pO, pL, attn_vec);

  // 4. mean over heads -> bf16
  mean_heads<<<dim3(BT * DHEAD / 2 / 256), 256, 0, stream>>>(attn_vec, m_attn);

  // 5. out = m_attn @ w_out^T + b_out  (bf16 MFMA, fp32 out)
  gemm_mfma_bf16<float><<<dim3(HIDDEN / QK_BN, BT / QK_BM), 256, 0, stream>>>(
      m_attn, wout_bf, b_out, out, BT, HIDDEN, DHEAD);
}

// Round 10
// 277.157 us; speedup vs baseline: 1.7271x; 1.0300x over previous
//
#include <hip/hip_runtime.h>
#include <hip/hip_bf16.h>
#include <math.h>

// Problem constants
#define NHEAD 16
#define DHEAD 64
#define HIDDEN 1024
#define TSEQ 2048
#define BATCH 4
#define QKV_OUT 2112   // (2*16+1)*64
#define BT (BATCH * TSEQ)  // 8192

typedef __attribute__((ext_vector_type(8))) short bf16x8;
typedef __attribute__((ext_vector_type(4))) float floatx4;

static __device__ __forceinline__ short f2bf(float x) {
  __hip_bfloat16 h = __float2bfloat16(x);
  return *reinterpret_cast<short*>(&h);
}

#define MFMA16(a, b, c) __builtin_amdgcn_mfma_f32_16x16x32_bf16(a, b, c, 0, 0, 0)

// ---------------------------------------------------------------------------
// fp32 -> bf16 conversion, 8 elems/thread. n must be divisible by 8.
// ---------------------------------------------------------------------------
__global__ __launch_bounds__(256) void f32_to_bf16(
    const float* __restrict__ src, short* __restrict__ dst, int n) {
  const int i = (blockIdx.x * 256 + threadIdx.x) * 8;
  if (i >= n) return;
  float4 a = *(const float4*)&src[i];
  float4 b = *(const float4*)&src[i + 4];
  short o[8];
  o[0] = f2bf(a.x); o[1] = f2bf(a.y); o[2] = f2bf(a.z); o[3] = f2bf(a.w);
  o[4] = f2bf(b.x); o[5] = f2bf(b.y); o[6] = f2bf(b.z); o[7] = f2bf(b.w);
  *(uint4*)&dst[i] = *(uint4*)o;
}

// ---------------------------------------------------------------------------
// MFMA bf16 GEMM: C[M][N] = A[M][K] @ B[N][K]^T + bias[N].
// BM=128, BN=64, BK=64; 4 waves 2x2; wave tile 64x32. Pad 72 shorts/row.
// ONLY change vs the round-7 verified kernel: 1D grid + XCD-chunked
// bijective swizzle (nwg % 8 == 0). Default round-robin scatters the ~33
// consecutive bx-tiles sharing one A row-panel across 8 XCDs (8x A-refetch,
// L3-latency misses -> the ~145us latency stall). The remap
// lid = (bid&7)*(nwg/8) + (bid>>3), bx = lid % nbx (fastest) pins each
// contiguous run to ONE XCD so the A-panel stays L2-hot.
// ---------------------------------------------------------------------------
#define QK_BM 128
#define QK_BN 64
#define QK_BK 64

template <typename OUT_T>
__global__ __launch_bounds__(256) void gemm_mfma_bf16(
    const short* __restrict__ A, const short* __restrict__ B,
    const float* __restrict__ bias, OUT_T* __restrict__ C,
    int M, int N, int K) {
  __shared__ short As[QK_BM][72];
  __shared__ short Bs[QK_BN][72];

  const int nbx = N / QK_BN;
  const int nwg = nbx * (M / QK_BM);
  const int cpx = nwg >> 3;  // nwg % 8 == 0 for both launch shapes
  const int bid = (int)blockIdx.x;
  const int lid = (bid & 7) * cpx + (bid >> 3);
  const int bx = lid % nbx;
  const int by = lid / nbx;

  const int tid = threadIdx.x;
  const int lane = tid & 63;
  const int wv = tid >> 6;
  const int ln = lane & 15;
  const int grp = lane >> 4;
  const int wm = wv >> 1;
  const int wn = wv & 1;
  const int rowbase = by * QK_BM;
  const int colbase = bx * QK_BN;

  const int ar = tid >> 1, ac = (tid & 1) * 32;
  const int br = tid >> 2, bc = (tid & 3) * 16;

  floatx4 acc[4][2];
#pragma unroll
  for (int m = 0; m < 4; ++m)
#pragma unroll
    for (int n = 0; n < 2; ++n) acc[m][n] = (floatx4){0.f, 0.f, 0.f, 0.f};

  const short* ap = A + (size_t)(rowbase + ar) * K + ac;
  const short* bp = B + (size_t)(colbase + br) * K + bc;

  // prologue: K-tile 0 into registers
  uint4 a0 = *(const uint4*)(ap + 0);
  uint4 a1 = *(const uint4*)(ap + 8);
  uint4 a2 = *(const uint4*)(ap + 16);
  uint4 a3 = *(const uint4*)(ap + 24);
  uint4 b0 = *(const uint4*)(bp + 0);
  uint4 b1 = *(const uint4*)(bp + 8);

  for (int k0 = 0; k0 < K; k0 += QK_BK) {
    __syncthreads();  // previous iteration's LDS reads done
    *(uint4*)&As[ar][ac + 0] = a0;
    *(uint4*)&As[ar][ac + 8] = a1;
    *(uint4*)&As[ar][ac + 16] = a2;
    *(uint4*)&As[ar][ac + 24] = a3;
    *(uint4*)&Bs[br][bc + 0] = b0;
    *(uint4*)&Bs[br][bc + 8] = b1;
    __syncthreads();

    // issue next K-tile loads now; they drain under the MFMAs below
    if (k0 + QK_BK < K) {
      ap += QK_BK;
      bp += QK_BK;
      a0 = *(const uint4*)(ap + 0);
      a1 = *(const uint4*)(ap + 8);
      a2 = *(const uint4*)(ap + 16);
      a3 = *(const uint4*)(ap + 24);
      b0 = *(const uint4*)(bp + 0);
      b1 = *(const uint4*)(bp + 8);
    }

#pragma unroll
    for (int ks = 0; ks < 2; ++ks) {
      bf16x8 bfrag[2];
#pragma unroll
      for (int n = 0; n < 2; ++n)
        bfrag[n] = *(const bf16x8*)&Bs[wn * 32 + n * 16 + ln][ks * 32 + grp * 8];
#pragma unroll
      for (int m = 0; m < 4; ++m) {
        bf16x8 af = *(const bf16x8*)&As[wm * 64 + m * 16 + ln][ks * 32 + grp * 8];
#pragma unroll
        for (int n = 0; n < 2; ++n)
          acc[m][n] = MFMA16(af, bfrag[n], acc[m][n]);
      }
    }
  }

#pragma unroll
  for (int n = 0; n < 2; ++n) {
    const int col = colbase + wn * 32 + n * 16 + ln;
    const float bv = bias[col];
#pragma unroll
    for (int m = 0; m < 4; ++m) {
#pragma unroll
      for (int r = 0; r < 4; ++r) {
        const int row = rowbase + wm * 64 + m * 16 + grp * 4 + r;
        const float v = acc[m][n][r] + bv;
        if constexpr (sizeof(OUT_T) == 2)
          C[(size_t)row * N + col] = f2bf(v);
        else
          C[(size_t)row * N + col] = v;
      }
    }
  }
}

// ---------------------------------------------------------------------------
// Transpose V: vt[b][d][t] = qkv_bf16[b*T + t][2048 + d]
// ---------------------------------------------------------------------------
__global__ __launch_bounds__(256) void transpose_v(
    const short* __restrict__ qkv, short* __restrict__ vt) {
  __shared__ short tile[64][72];
  const int tt = blockIdx.x;
  const int b = blockIdx.y;
  const int tid = threadIdx.x;
  const int li = tid >> 2;
  const int lc = (tid & 3) * 16;

  const short* src = qkv + (size_t)(b * TSEQ + tt * 64 + li) * QKV_OUT + 2048 + lc;
  *(uint4*)&tile[li][lc] = *(const uint4*)src;
  *(uint4*)&tile[li][lc + 8] = *(const uint4*)(src + 8);
  __syncthreads();
  short tmp[16];
#pragma unroll
  for (int u = 0; u < 16; ++u) tmp[u] = tile[lc + u][li];
  short* dst = vt + (size_t)(b * 64 + li) * TSEQ + tt * 64 + lc;
  *(uint4*)dst = *(uint4*)&tmp[0];
  *(uint4*)(dst + 8) = *(uint4*)&tmp[8];
}

// ---------------------------------------------------------------------------
// Split-j MFMA bf16 causal flash attention, QB=128 / 8-wave (round-7
// verified, 106.1 us — UNTOUCHED). Each staged 64x64 K/V tile feeds 8 waves
// (128 q-rows). Chunks <=16 j-tiles; it<8 single chunk writes attn_vec
// directly; it>=8 has exactly 2 chunks -> partials.
// ---------------------------------------------------------------------------
#define QB 128

__global__ __launch_bounds__(512) void attn_partial(
    const short* __restrict__ qkv, const short* __restrict__ vt,
    float* __restrict__ attn_vec, float* __restrict__ pO,
    float* __restrict__ pL) {
  __shared__ short Ks[64][72];   // [j][d]
  __shared__ short Vt[64][72];   // [d][j]
  __shared__ short Ps[128][72];  // [q][j], per-wave 16-row slices

  const int x = (int)gridDim.x - 1 - (int)blockIdx.x;  // big blocks first
  int it, jc;
  if (x < 8) {
    it = x; jc = 0;                       // njt = 2it+2 <= 16: single chunk
  } else {
    it = 8 + ((x - 8) >> 1); jc = (x - 8) & 1;  // it>=8: 2 chunks of <=16
  }
  const int jstart = jc * 16;
  const int jend = min(jstart + 16, 2 * it + 2);

  const int tid = threadIdx.x;  // 0..511
  const int h = blockIdx.y;
  const int b = blockIdx.z;
  const int lane = tid & 63;
  const int wv = tid >> 6;      // 0..7
  const int ln = lane & 15;
  const int grp = lane >> 4;
  const int qbase = wv * 16;    // 0..112: wave's 16 q-rows within the 128
  const int sr = tid >> 3;          // staging row 0..63
  const int sc = (tid & 7) * 8;     // staging col (shorts) 0..56
  const float CEXP = 0.18033688f;   // 0.125 * log2(e)

  // Q B-fragment (persistent): B[k=d][n=q]
  const short* qptr =
      qkv + (size_t)(b * TSEQ + it * QB + qbase + ln) * QKV_OUT + h * 64;
  const bf16x8 bq0 = *(const bf16x8*)(qptr + grp * 8);
  const bf16x8 bq1 = *(const bf16x8*)(qptr + 32 + grp * 8);

  floatx4 oT[4];
#pragma unroll
  for (int m = 0; m < 4; ++m) oT[m] = (floatx4){0.f, 0.f, 0.f, 0.f};
  float lsum = 0.f;

  // prefetch first tile of this chunk (1 uint4 K + 1 uint4 V per thread)
  const short* ks0 =
      qkv + (size_t)(b * TSEQ + jstart * 64 + sr) * QKV_OUT + 1024 + h * 64 + sc;
  const short* vs0 = vt + (size_t)(b * 64 + sr) * TSEQ + jstart * 64 + sc;
  uint4 kr = *(const uint4*)ks0;
  uint4 vr = *(const uint4*)vs0;

  for (int jt = jstart; jt < jend; ++jt) {
    __syncthreads();  // all waves done reading previous Ks/Vt
    *(uint4*)&Ks[sr][sc] = kr;
    *(uint4*)&Vt[sr][sc] = vr;
    __syncthreads();

    // prefetch next tile (latency hidden under compute)
    if (jt + 1 < jend) {
      const short* kn =
          qkv + (size_t)(b * TSEQ + (jt + 1) * 64 + sr) * QKV_OUT + 1024 + h * 64 + sc;
      const short* vn = vt + (size_t)(b * 64 + sr) * TSEQ + (jt + 1) * 64 + sc;
      kr = *(const uint4*)kn;
      vr = *(const uint4*)vn;
    }

    // wave-uniform skip: this wave's q-rows all above the diagonal?
    const int qg = it * QB + qbase;  // wave's lowest q-row
    if (qg + 15 >= jt * 64) {
      // S^T = K @ Q^T: 4 m-tiles (j), 2 k-steps (d)
      floatx4 st[4];
      __builtin_amdgcn_s_setprio(1);
#pragma unroll
      for (int m = 0; m < 4; ++m) {
        bf16x8 ak0 = *(const bf16x8*)&Ks[m * 16 + ln][grp * 8];
        bf16x8 ak1 = *(const bf16x8*)&Ks[m * 16 + ln][32 + grp * 8];
        floatx4 a = (floatx4){0.f, 0.f, 0.f, 0.f};
        a = MFMA16(ak0, bq0, a);
        a = MFMA16(ak1, bq1, a);
        st[m] = a;
      }
      __builtin_amdgcn_s_setprio(0);

      // causal mask: j-elements above this lane's q-row -> -inf
      const int dj = qg + ln - jt * 64;  // elements j_local > dj are masked
      if (dj < 63) {
#pragma unroll
        for (int m = 0; m < 4; ++m)
#pragma unroll
          for (int r = 0; r < 4; ++r)
            if (m * 16 + grp * 4 + r > dj) st[m][r] = -INFINITY;
      }

      // P = exp2(CEXP * s), accumulate l, packed bf16x4 store to Ps
#pragma unroll
      for (int m = 0; m < 4; ++m) {
        float p0 = exp2f(CEXP * st[m][0]);
        float p1 = exp2f(CEXP * st[m][1]);
        float p2 = exp2f(CEXP * st[m][2]);
        float p3 = exp2f(CEXP * st[m][3]);
        lsum += (p0 + p1) + (p2 + p3);
        short pk[4] = {f2bf(p0), f2bf(p1), f2bf(p2), f2bf(p3)};
        *(uint2*)&Ps[qbase + ln][m * 16 + grp * 4] = *(uint2*)pk;
      }

      // O^T += V^T(A) @ P^T(B)  (same-wave LDS write->read, in-order DS)
      bf16x8 bp0 = *(const bf16x8*)&Ps[qbase + ln][grp * 8];
      bf16x8 bp1 = *(const bf16x8*)&Ps[qbase + ln][32 + grp * 8];
      __builtin_amdgcn_s_setprio(1);
#pragma unroll
      for (int m = 0; m < 4; ++m) {
        bf16x8 av0 = *(const bf16x8*)&Vt[m * 16 + ln][grp * 8];
        bf16x8 av1 = *(const bf16x8*)&Vt[m * 16 + ln][32 + grp * 8];
        oT[m] = MFMA16(av0, bp0, oT[m]);
        oT[m] = MFMA16(av1, bp1, oT[m]);
      }
      __builtin_amdgcn_s_setprio(0);
    }
  }

  // reduce l across grp (lanes with same ln share q)
  lsum += __shfl_xor(lsum, 16);
  lsum += __shfl_xor(lsum, 32);

  if (it < 8) {
    // single chunk: normalize and write attn_vec directly
    const float inv = 1.f / lsum;
    float* orow =
        attn_vec + ((size_t)(b * NHEAD + h) * TSEQ + it * QB + qbase + ln) * DHEAD;
#pragma unroll
    for (int m = 0; m < 4; ++m) {
      float4 o4;
      o4.x = oT[m][0] * inv;
      o4.y = oT[m][1] * inv;
      o4.z = oT[m][2] * inv;
      o4.w = oT[m][3] * inv;
      *(float4*)&orow[m * 16 + grp * 4] = o4;
    }
  } else {
    // write unnormalized partial: slot = (it-8)*2 + jc, 16 slots per (b,h)
    const int slot = (it - 8) * 2 + jc;
    const size_t sbase = (size_t)(b * NHEAD + h) * 16 + slot;
    float* prow = pO + sbase * 8192 + (size_t)(qbase + ln) * 64;
#pragma unroll
    for (int m = 0; m < 4; ++m) {
      float4 o4;
      o4.x = oT[m][0]; o4.y = oT[m][1]; o4.z = oT[m][2]; o4.w = oT[m][3];
      *(float4*)&prow[m * 16 + grp * 4] = o4;
    }
    if (grp == 0) pL[sbase * 128 + qbase + ln] = lsum;
  }
}

// ---------------------------------------------------------------------------
// Combine partials for it>=8: exactly 2 chunks per it. Sum O^T + l,
// normalize, write attn_vec. Block = (it-8, h, b); thread -> q = tid>>1,
// 32 d-cols each.
// ---------------------------------------------------------------------------
__global__ __launch_bounds__(256) void attn_combine(
    const float* __restrict__ pO, const float* __restrict__ pL,
    float* __restrict__ attn_vec) {
  const int it = 8 + blockIdx.x;  // 8..15
  const int h = blockIdx.y;
  const int b = blockIdx.z;
  const int q = threadIdx.x >> 1;           // 0..127
  const int dbase = (threadIdx.x & 1) * 32;
  const size_t base = (size_t)(b * NHEAD + h) * 16 + (it - 8) * 2;

  float4 acc[8];
#pragma unroll
  for (int u = 0; u < 8; ++u) acc[u] = (float4){0.f, 0.f, 0.f, 0.f};
  float l = 0.f;
#pragma unroll
  for (int c = 0; c < 2; ++c) {
    const float* pr = pO + (base + c) * 8192 + (size_t)q * 64 + dbase;
#pragma unroll
    for (int u = 0; u < 8; ++u) {
      float4 v = *(const float4*)&pr[u * 4];
      acc[u].x += v.x; acc[u].y += v.y; acc[u].z += v.z; acc[u].w += v.w;
    }
    l += pL[(base + c) * 128 + q];
  }
  const float inv = 1.f / l;
  float* orow =
      attn_vec + ((size_t)(b * NHEAD + h) * TSEQ + it * QB + q) * DHEAD + dbase;
#pragma unroll
  for (int u = 0; u < 8; ++u) {
    float4 o4;
    o4.x = acc[u].x * inv; o4.y = acc[u].y * inv;
    o4.z = acc[u].z * inv; o4.w = acc[u].w * inv;
    *(float4*)&orow[u * 4] = o4;
  }
}

// ---------------------------------------------------------------------------
// Mean over heads -> bf16 (feeds the MFMA out-projection). 2 elems/thread.
// ---------------------------------------------------------------------------
__global__ __launch_bounds__(256) void mean_heads(
    const float* __restrict__ attn_vec, short* __restrict__ m) {
  const int gid = blockIdx.x * 256 + threadIdx.x;  // over BT*64/2
  const int d2 = (gid & 31) * 2;
  const int t = (gid >> 5) & (TSEQ - 1);
  const int b = gid >> 16;
  float s0 = 0.f, s1 = 0.f;
#pragma unroll
  for (int h = 0; h < NHEAD; ++h) {
    const float* p = &attn_vec[(((size_t)(b * NHEAD + h) * TSEQ) + t) * DHEAD + d2];
    s0 += p[0];
    s1 += p[1];
  }
  short pk[2] = {f2bf(s0 * (1.f / 16.f)), f2bf(s1 * (1.f / 16.f))};
  *(uint*)&m[gid * 2] = *(uint*)pk;
}

// ---------------------------------------------------------------------------
extern "C" void kernel_launch(void* const* d_in, const int* in_sizes, int n_in,
                              void* d_out, int out_size, void* d_ws, size_t ws_size,
                              hipStream_t stream) {
  const float* x     = (const float*)d_in[0];  // [4,2048,1024]
  const float* w_qkv = (const float*)d_in[1];  // [2112,1024]
  const float* b_qkv = (const float*)d_in[2];  // [2112]
  const float* w_out = (const float*)d_in[3];  // [1024,64]
  const float* b_out = (const float*)d_in[4];  // [1024]

  float* out      = (float*)d_out;              // [4,2048,1024]
  float* attn_vec = out + (size_t)BT * HIDDEN;  // [4,16,2048,64]

  // Workspace layout. x_bf/w_bf are dead after the QKV GEMM; the partial
  // buffers (written by attn_partial, later) overlap them.
  short* qkv_bf  = (short*)d_ws;                           // [8192][2112] bf16
  short* vt_bf   = qkv_bf + (size_t)BT * QKV_OUT;          // [4][64][2048] bf16
  short* wout_bf = vt_bf + (size_t)BATCH * DHEAD * TSEQ;   // [1024][64] bf16
  short* m_attn  = wout_bf + (size_t)HIDDEN * DHEAD;       // [8192][64] bf16
  char*  xbase   = (char*)(m_attn + (size_t)BT * DHEAD);
  short* x_bf    = (short*)xbase;                          // [8192][1024] bf16
  short* w_bf    = x_bf + (size_t)BT * HIDDEN;             // [2112][1024] bf16
  float* pO      = (float*)xbase;                          // [64*16][128][64] f32
  float* pL      = pO + (size_t)64 * 16 * 8192;            // [64*16][128] f32

  // 0. convert inputs to bf16
  f32_to_bf16<<<dim3(BT * HIDDEN / 8 / 256), 256, 0, stream>>>(
      x, x_bf, BT * HIDDEN);
  f32_to_bf16<<<dim3(QKV_OUT * HIDDEN / 8 / 256), 256, 0, stream>>>(
      w_qkv, w_bf, QKV_OUT * HIDDEN);
  f32_to_bf16<<<dim3(HIDDEN * DHEAD / 8 / 256), 256, 0, stream>>>(
      w_out, wout_bf, HIDDEN * DHEAD);

  // 1. qkv = x @ w_qkv^T + b_qkv  (XCD-swizzled 1D grid)
  gemm_mfma_bf16<short>
      <<<dim3((QKV_OUT / QK_BN) * (BT / QK_BM)), 256, 0, stream>>>(
          x_bf, w_bf, b_qkv, qkv_bf, BT, QKV_OUT, HIDDEN);

  // 2. pre-transpose V: vt[b][d][t]
  transpose_v<<<dim3(TSEQ / 64, BATCH), 256, 0, stream>>>(qkv_bf, vt_bf);

  // 3. split-j MFMA causal flash attention (QB=128, 8 waves, 24 (it,jc) pairs)
  attn_partial<<<dim3(24, NHEAD, BATCH), 512, 0, stream>>>(
      qkv_bf, vt_bf, attn_vec, pO, pL);

  // 3b. combine partials for it>=8 (2 chunks each)
  attn_combine<<<dim3(8, NHEAD, BATCH), 256, 0, stream>>>(pO, pL, attn_vec);

  // 4. mean over heads -> bf16
  mean_heads<<<dim3(BT * DHEAD / 2 / 256), 256, 0, stream>>>(attn_vec, m_attn);

  // 5. out = m_attn @ w_out^T + b_out  (XCD-swizzled 1D grid, fp32 out)
  gemm_mfma_bf16<float>
      <<<dim3((HIDDEN / QK_BN) * (BT / QK_BM)), 256, 0, stream>>>(
          m_attn, wout_bf, b_out, out, BT, HIDDEN, DHEAD);
}